// Round 10
// baseline (191.746 us; speedup 1.0000x reference)
//
#include <hip/hip_runtime.h>
#include <hip/hip_fp16.h>

#define NATOMS 768
#define NM1    767
#define NEDGE  (768*767)       // 589056
#define DIM    64
#define NC     50
#define GAPF   (5.0f/49.0f)
#define NIGAP  (-49.0f/5.0f)
#define G      512
#define STEPF  (5.0f/511.0f)
#define INVSTEP (511.0f/5.0f)
#define LN2F   0.693147180559945f

// ws layout (float offsets)
#define WS_H     0              // 768*64 f32
#define WS_NWA   49152          // 768*64 f16 (24576 float slots)
#define WS_NWB   73728          // 768*64 f16
#define WS_HA    98304          // 768 f32 (+pad)
#define WS_DISTT 99328          // 768*768 f32
#define WS_TT    689152         // 4 tables * 512*64 __half2 = 131072 float slots

#define TBL_BYTES   131072      // one layer's f16 table (G*DIM*4 B)
#define CONV_SMEM   (TBL_BYTES + 16*3*64*4 + 3*192*4)   // 145664 B

__device__ __forceinline__ float softplus05(float x) {
    float bx = 0.5f * x;
    return (bx > 14.0f) ? x : 2.0f * __logf(1.0f + __expf(bx));
}
__device__ __forceinline__ int lane_bcast_i(int v, int l) {
    return __builtin_amdgcn_readlane(v, l);
}
__device__ __forceinline__ float lane_bcast_f(float v, int l) {
    return __uint_as_float((unsigned)__builtin_amdgcn_readlane((int)__float_as_uint(v), l));
}

// ============ prologue: f16 tables + embed/nw0(f16) + dist transpose ============
// (verbatim round-9 proven kernel)
__global__ __launch_bounds__(256)
void k_pre(const int* __restrict__ types, const float* __restrict__ dist,
           const float* __restrict__ emb, const float* __restrict__ w1all,
           const float* __restrict__ pw1, const float* __restrict__ pb1,
           const float* __restrict__ pw2, const float* __restrict__ pb2,
           const float* __restrict__ row1, const float* __restrict__ rob1,
           float* __restrict__ ws) {
    __shared__ float s_t[4 * 64];
    const int tid = threadIdx.x, widx = tid >> 6, c = tid & 63;
    float*  h     = ws + WS_H;
    __half* nwh   = (__half*)(ws + WS_NWA);
    float*  distT = ws + WS_DISTT;
    __half* TTh   = (__half*)(ws + WS_TT);
    const int b = blockIdx.x;

    if (b < 512) {
        const int w = b * 4 + widx, tbl = w >> 9, g = w & 511;
        const float d = g * STEPF;
        float val;
        if (tbl < 3) {
            const float* W1 = pw1 + tbl * NC * DIM;
            float t1 = pb1[tbl * DIM + c];
            for (int k = 0; k < NC; ++k) {
                float x = d - GAPF * (float)k;
                t1 = fmaf(__expf(NIGAP * x * x), W1[k * DIM + c], t1);
            }
            s_t[widx * 64 + c] = softplus05(t1);     // wave-local lockstep
            const float* W2 = pw2 + tbl * DIM * DIM;
            val = pb2[tbl * DIM + c];
            #pragma unroll 8
            for (int k = 0; k < DIM; ++k)
                val = fmaf(s_t[widx * 64 + k], W2[k * DIM + c], val);
        } else {
            val = rob1[c];
            for (int k = 0; k < NC; ++k) {
                float x = d - GAPF * (float)k;
                val = fmaf(__expf(NIGAP * x * x), row1[(2 + k) * DIM + c], val);
            }
        }
        // paired f16 layout: entry (g,c) holds (T[g][c], T[g+1][c]) as __half2
        __half* TTt = TTh + tbl * (G * DIM * 2);
        TTt[(g * DIM + c) * 2] = __float2half(val);
        if (g > 0) TTt[((g - 1) * DIM + c) * 2 + 1] = __float2half(val);
    } else if (b < 704) {
        const int i = (b - 512) * 4 + widx;
        float hv = emb[types[i] * DIM + c];
        h[i * DIM + c] = hv;
        s_t[widx * 64 + c] = hv;                     // wave-local
        float acc = 0.0f;
        #pragma unroll 8
        for (int k = 0; k < DIM; ++k)
            acc = fmaf(s_t[widx * 64 + k], w1all[k * DIM + c], acc);
        nwh[i * DIM + c] = __float2half(acc);
    } else {
        const int idx = (b - 704) * 256 + tid;       // < 768*768
        const int j = idx / NATOMS, i = idx - j * NATOMS;
        distT[idx] = (i == j) ? 0.0f : dist[i * NM1 + (j - (j > i))];
    }
}

// ============ conv layer, LDS-staged table: block owns dest-triple ============
// 256 blocks x 16 waves (1024 thr, 1 block/CU). Stage the 128 KB f16 table
// into LDS once, then R8's verified triple-dest inner loop with ds_read.
// wave widx covers sources [widx*48, widx*48+48); waves 0..2 run node MLP.
__global__ __launch_bounds__(1024)
void k_edgeupd_lds(const __half2* __restrict__ TTl, const float* __restrict__ distT,
                   const __half* __restrict__ nwin,
                   const float* __restrict__ qw1, const float* __restrict__ qb1,
                   const float* __restrict__ qw2, const float* __restrict__ qb2,
                   float* __restrict__ h,
                   const float* __restrict__ wnext, __half* __restrict__ nwout,
                   const float* __restrict__ auw1, const float* __restrict__ aub1,
                   const float* __restrict__ auw2, const float* __restrict__ aub2,
                   float* __restrict__ ha, int last) {
    extern __shared__ char smem[];
    float* s_part = (float*)(smem + TBL_BYTES);          // [16][3][64]
    float* s_updA = (float*)(smem + TBL_BYTES + 12288);  // [3][192]
    const int tid = threadIdx.x, widx = tid >> 6, c = tid & 63;
    const int j0 = blockIdx.x * 3;
    const int s0 = widx * 48;

    // ---- stage table: 131072 B = 8192 float4, 1024 threads x 8 ----
    {
        const float4* src4 = (const float4*)TTl;
        float4* dst4 = (float4*)smem;
        #pragma unroll
        for (int k = 0; k < 8; ++k) dst4[tid + k * 1024] = src4[tid + k * 1024];
    }
    __syncthreads();

    // ---- per-lane (g,f) for this wave's 48 sources (lanes 48-63 idle-safe) ----
    const int cS = (c < 48) ? c : 47;
    float dA = distT[j0 * NATOMS + s0 + cS];
    float dB = distT[(j0 + 1) * NATOMS + s0 + cS];
    float dC = distT[(j0 + 2) * NATOMS + s0 + cS];
    float pA = dA * INVSTEP, pB = dB * INVSTEP, pC = dC * INVSTEP;
    int gA = (int)pA, gB = (int)pB, gC = (int)pC;
    gA = (gA < 0) ? 0 : ((gA > 510) ? 510 : gA);
    gB = (gB < 0) ? 0 : ((gB > 510) ? 510 : gB);
    gC = (gC < 0) ? 0 : ((gC > 510) ? 510 : gC);
    float fA = pA - (float)gA, fB = pB - (float)gB, fC = pC - (float)gC;
    int kA = gA * 256, kB = gB * 256, kC = gC * 256;     // byte offset of f16 row

    const char* Tb = (const char*)smem + c * 4;          // lane's column
    float acc0 = 0.0f, acc1 = 0.0f, acc2 = 0.0f;
    #pragma unroll 8
    for (int it = 0; it < 48; ++it) {
        float nwv = __half2float(nwin[(s0 + it) * DIM + c]);
        {
            float2 tt = __half22float2(*(const __half2*)(Tb + lane_bcast_i(kA, it)));
            float e = fmaf(lane_bcast_f(fA, it), tt.y - tt.x, tt.x);
            acc0 = fmaf(e, nwv, acc0);
        }
        {
            float2 tt = __half22float2(*(const __half2*)(Tb + lane_bcast_i(kB, it)));
            float e = fmaf(lane_bcast_f(fB, it), tt.y - tt.x, tt.x);
            acc1 = fmaf(e, nwv, acc1);
        }
        {
            float2 tt = __half22float2(*(const __half2*)(Tb + lane_bcast_i(kC, it)));
            float e = fmaf(lane_bcast_f(fC, it), tt.y - tt.x, tt.x);
            acc2 = fmaf(e, nwv, acc2);
        }
    }
    s_part[(widx * 3 + 0) * 64 + c] = acc0;
    s_part[(widx * 3 + 1) * 64 + c] = acc1;
    s_part[(widx * 3 + 2) * 64 + c] = acc2;
    __syncthreads();

    if (widx < 3) {
        const int jt = j0 + widx;
        float tot = 0.0f;
        #pragma unroll
        for (int w16 = 0; w16 < 16; ++w16) tot += s_part[(w16 * 3 + widx) * 64 + c];
        // remove fake i==j term: distT diag=0 -> g=0,f=0 -> e = T[0][c] exactly
        float2 t0 = __half22float2(*(const __half2*)Tb);
        tot -= t0.x * __half2float(nwin[jt * DIM + c]);
        // node MLP (wave-local LDS, lockstep)
        float* su = s_updA + widx * 192;
        su[c] = tot;
        float t = qb1[c];
        #pragma unroll 8
        for (int k = 0; k < DIM; ++k) t = fmaf(su[k], qw1[k * DIM + c], t);
        su[64 + c] = softplus05(t);
        float o = qb2[c];
        #pragma unroll 8
        for (int k = 0; k < DIM; ++k) o = fmaf(su[64 + k], qw2[k * DIM + c], o);
        float hn = h[jt * DIM + c] + o;
        h[jt * DIM + c] = hn;
        su[128 + c] = hn;
        if (!last) {
            float v = 0.0f;
            #pragma unroll 8
            for (int k = 0; k < DIM; ++k) v = fmaf(su[128 + k], wnext[k * DIM + c], v);
            nwout[jt * DIM + c] = __float2half(v);
        } else {
            float t2 = aub1[c];
            #pragma unroll 8
            for (int k = 0; k < DIM; ++k) t2 = fmaf(su[128 + k], auw1[k * DIM + c], t2);
            t2 = ((t2 > 20.0f) ? t2 : __logf(1.0f + __expf(t2))) - LN2F;
            float v = t2 * auw2[c];
            #pragma unroll
            for (int s = 32; s > 0; s >>= 1) v += __shfl_down(v, s, 64);
            if (c == 0) ha[jt] = v + aub2[0];
        }
    }
}

// ============ conv layer fallback (verbatim round-9 proven kernel) ============
__global__ __launch_bounds__(512)
void k_edgeupd(const __half2* __restrict__ TTl, const float* __restrict__ distT,
               const __half* __restrict__ nwin,
               const float* __restrict__ qw1, const float* __restrict__ qb1,
               const float* __restrict__ qw2, const float* __restrict__ qb2,
               float* __restrict__ h,
               const float* __restrict__ wnext, __half* __restrict__ nwout,
               const float* __restrict__ auw1, const float* __restrict__ aub1,
               const float* __restrict__ auw2, const float* __restrict__ aub2,
               float* __restrict__ ha, int last) {
    __shared__ float s_part[8][64];
    __shared__ float s_upd[192];
    const int tid = threadIdx.x, widx = tid >> 6, c = tid & 63;
    const int j = blockIdx.x;
    const int s0 = widx * 96;

    const char* TTb = (const char*)TTl + c * 4;
    float csum = 0.0f;
    {
        float d = distT[j * NATOMS + s0 + c];
        float pos = d * INVSTEP;
        int g = (int)pos;
        g = (g < 0) ? 0 : ((g > 510) ? 510 : g);
        float f = pos - (float)g;
        int kx = g * 256;
        #pragma unroll 8
        for (int it = 0; it < 64; ++it) {
            int kxu = lane_bcast_i(kx, it);
            float fu = lane_bcast_f(f, it);
            float2 tt = __half22float2(*(const __half2*)(TTb + kxu));
            float e = fmaf(fu, tt.y - tt.x, tt.x);
            float nwv = __half2float(nwin[(s0 + it) * DIM + c]);
            csum = fmaf(e, nwv, csum);
        }
    }
    {
        float d = distT[j * NATOMS + s0 + 64 + (c & 31)];
        float pos = d * INVSTEP;
        int g = (int)pos;
        g = (g < 0) ? 0 : ((g > 510) ? 510 : g);
        float f = pos - (float)g;
        int kx = g * 256;
        #pragma unroll 8
        for (int it = 0; it < 32; ++it) {
            int kxu = lane_bcast_i(kx, it);
            float fu = lane_bcast_f(f, it);
            float2 tt = __half22float2(*(const __half2*)(TTb + kxu));
            float e = fmaf(fu, tt.y - tt.x, tt.x);
            float nwv = __half2float(nwin[(s0 + 64 + it) * DIM + c]);
            csum = fmaf(e, nwv, csum);
        }
    }
    s_part[widx][c] = csum;
    __syncthreads();

    if (widx == 0) {
        float tot = 0.0f;
        #pragma unroll
        for (int w8 = 0; w8 < 8; ++w8) tot += s_part[w8][c];
        float2 t0 = __half22float2(*(const __half2*)TTb);
        tot -= t0.x * __half2float(nwin[j * DIM + c]);
        s_upd[c] = tot;
        float t = qb1[c];
        #pragma unroll 8
        for (int k = 0; k < DIM; ++k) t = fmaf(s_upd[k], qw1[k * DIM + c], t);
        s_upd[64 + c] = softplus05(t);
        float o = qb2[c];
        #pragma unroll 8
        for (int k = 0; k < DIM; ++k) o = fmaf(s_upd[64 + k], qw2[k * DIM + c], o);
        float hn = h[j * DIM + c] + o;
        h[j * DIM + c] = hn;
        s_upd[128 + c] = hn;
        if (!last) {
            float v = 0.0f;
            #pragma unroll 8
            for (int k = 0; k < DIM; ++k) v = fmaf(s_upd[128 + k], wnext[k * DIM + c], v);
            nwout[j * DIM + c] = __float2half(v);
        } else {
            float t2 = aub1[c];
            #pragma unroll 8
            for (int k = 0; k < DIM; ++k) t2 = fmaf(s_upd[128 + k], auw1[k * DIM + c], t2);
            t2 = ((t2 > 20.0f) ? t2 : __logf(1.0f + __expf(t2))) - LN2F;
            float v = t2 * auw2[c];
            #pragma unroll
            for (int s = 32; s > 0; s >>= 1) v += __shfl_down(v, s, 64);
            if (c == 0) ha[j] = v + aub2[0];
        }
    }
}

// ============ readout (verbatim round-9 proven kernel) ============
__global__ __launch_bounds__(256)
void k_ro(const float* __restrict__ dist, const int* __restrict__ src,
          const int* __restrict__ dst, const float* __restrict__ ha,
          const __half2* __restrict__ TTro,
          const float* __restrict__ row1, const float* __restrict__ row2,
          const float* __restrict__ rob2, float* __restrict__ out) {
    __shared__ float4 s_pre[4][64];
    __shared__ float s_h[4][16 * 65];
    __shared__ float s_w2[128];
    const int tid = threadIdx.x, widx = tid >> 6, c = tid & 63;
    if (tid < 128) s_w2[tid] = row2[tid];
    __syncthreads();
    const int ebase = (blockIdx.x * 4 + widx) * 64;
    {
        int eg = ebase + c;
        float d = dist[eg];
        float pos = d * INVSTEP;
        int kk = (int)pos;
        kk = (kk < 0) ? 0 : ((kk > 510) ? 510 : kk);
        float fa = ha[src[eg]], fb = ha[dst[eg]];
        s_pre[widx][c] = make_float4(__int_as_float(kk * 256), pos - (float)kk, fa, fb);
    }
    const char* TTb2 = (const char*)TTro + c * 4;
    const float wa = row1[c], wb = row1[DIM + c];
    const int e2 = (c >> 1) & 15, p2 = c & 1, kh = c >> 5;
    const float bias2 = (kh == 0) ? rob2[p2] : 0.0f;
    float* sh = s_h[widx];
    #pragma unroll
    for (int ch = 0; ch < 4; ++ch) {
        #pragma unroll 4
        for (int e = 0; e < 16; ++e) {               // lane = channel
            float4 p = s_pre[widx][ch * 16 + e];
            float2 tt = __half22float2(*(const __half2*)(TTb2 + __float_as_int(p.x)));
            float hv = fmaf(p.y, tt.y - tt.x, tt.x);
            hv = fmaf(p.z, wa, hv);
            hv = fmaf(p.w, wb, hv);
            sh[e * 65 + c] = fmaxf(hv, 0.0f);
        }
        // lane = (khalf, edge, logit); half-k dot then combine
        float lsum = bias2;
        #pragma unroll 8
        for (int k8 = 0; k8 < 32; ++k8) {
            int k = kh * 32 + k8;
            lsum = fmaf(sh[e2 * 65 + k], s_w2[2 * k + p2], lsum);
        }
        lsum += __shfl_xor(lsum, 32, 64);
        float other = __shfl_xor(lsum, 1, 64);
        float m = fmaxf(lsum, other);
        float ea = __expf(lsum - m), eb = __expf(other - m);
        float r = ea / (ea + eb);
        if (c < 32) out[ebase * 2 + ch * 32 + c] = r;
    }
}

extern "C" void kernel_launch(void* const* d_in, const int* in_sizes, int n_in,
                              void* d_out, int out_size, void* d_ws, size_t ws_size,
                              hipStream_t stream) {
    const int*   types = (const int*)d_in[0];
    const float* dist  = (const float*)d_in[1];
    const int*   srcI  = (const int*)d_in[2];
    const int*   dstI  = (const int*)d_in[3];
    const float* emb   = (const float*)d_in[4];
    const float* w1    = (const float*)d_in[5];
    const float* pw1   = (const float*)d_in[6];
    const float* pb1   = (const float*)d_in[7];
    const float* pw2   = (const float*)d_in[8];
    const float* pb2   = (const float*)d_in[9];
    const float* qw1   = (const float*)d_in[10];
    const float* qb1   = (const float*)d_in[11];
    const float* qw2   = (const float*)d_in[12];
    const float* qb2   = (const float*)d_in[13];
    const float* auw1  = (const float*)d_in[14];
    const float* aub1  = (const float*)d_in[15];
    const float* auw2  = (const float*)d_in[16];
    const float* aub2  = (const float*)d_in[17];
    const float* row1  = (const float*)d_in[18];
    const float* rob1  = (const float*)d_in[19];
    const float* row2  = (const float*)d_in[20];
    const float* rob2  = (const float*)d_in[21];

    float* ws   = (float*)d_ws;
    float* outp = (float*)d_out;
    const __half2* TT = (const __half2*)(ws + WS_TT);
    __half* nwbuf[2] = { (__half*)(ws + WS_NWA), (__half*)(ws + WS_NWB) };

    // LDS-staged conv valid on this device? (deterministic per process)
    int ldsOK = 0;
    {
        int dev = 0, maxLds = 0;
        if (hipGetDevice(&dev) == hipSuccess &&
            hipDeviceGetAttribute(&maxLds,
                hipDeviceAttributeMaxSharedMemoryPerMultiprocessor, dev) == hipSuccess &&
            maxLds >= CONV_SMEM &&
            hipFuncSetAttribute((const void*)k_edgeupd_lds,
                hipFuncAttributeMaxDynamicSharedMemorySize,
                CONV_SMEM) == hipSuccess)
            ldsOK = 1;
    }

    k_pre<<<3008, 256, 0, stream>>>(types, dist, emb, w1, pw1, pb1, pw2, pb2,
                                    row1, rob1, ws);
    for (int l = 0; l < 3; ++l) {
        if (ldsOK) {
            k_edgeupd_lds<<<256, 1024, CONV_SMEM, stream>>>(TT + l * (G * DIM),
                ws + WS_DISTT, nwbuf[l & 1],
                qw1 + l * DIM * DIM, qb1 + l * DIM,
                qw2 + l * DIM * DIM, qb2 + l * DIM,
                ws + WS_H,
                (l < 2) ? (w1 + (l + 1) * DIM * DIM) : w1, nwbuf[(l + 1) & 1],
                auw1, aub1, auw2, aub2, ws + WS_HA, (l == 2) ? 1 : 0);
        } else {
            k_edgeupd<<<768, 512, 0, stream>>>(TT + l * (G * DIM),
                ws + WS_DISTT, nwbuf[l & 1],
                qw1 + l * DIM * DIM, qb1 + l * DIM,
                qw2 + l * DIM * DIM, qb2 + l * DIM,
                ws + WS_H,
                (l < 2) ? (w1 + (l + 1) * DIM * DIM) : w1, nwbuf[(l + 1) & 1],
                auw1, aub1, auw2, aub2, ws + WS_HA, (l == 2) ? 1 : 0);
        }
    }
    k_ro<<<2301, 256, 0, stream>>>(dist, srcI, dstI, ws + WS_HA, TT + 3 * (G * DIM),
                                   row1, row2, rob2, outp);
}